// Round 3
// baseline (400.784 us; speedup 1.0000x reference)
//
#include <hip/hip_runtime.h>
#include <hip/hip_bf16.h>
#include <stdint.h>

// MultiHeadSelfAttention, B=1, S=4096, D_MODEL=768, H=12, Dk=64, causal.
// I/O is FP32 (per reference dtypes); bf16 tolerance permits bf16 MFMA inside.
// Launches:
//   0) cvt_f32_bf16 x5: x, Wq, Wk, Wv, Wo  fp32 -> bf16 in workspace
//   1) gemm_nt<1>: QKV projections (x @ W^T), epilogue scatters to [H][S][64] bf16
//   2) flash_attn: causal flash attention per (q-block, head) -> AO bf16
//   3) gemm_nt<0>: output projection AO @ Wo^T -> d_out FP32
// Workspace (bf16 elems): xb 3.1M | 4x W 0.59M | Qh/Kh/Vh 3x3.1M | AO 3.1M = 36.2 MB.

#define S_LEN  4096
#define DMODEL 768
#define NHEADS 12

typedef __attribute__((ext_vector_type(8))) __bf16 bf16x8;
typedef __attribute__((ext_vector_type(8))) unsigned short ushortx8;
typedef __attribute__((ext_vector_type(4))) float floatx4;

__device__ __forceinline__ unsigned short f2bf(float f) {
    unsigned int u = __float_as_uint(f);
    u += 0x7fffu + ((u >> 16) & 1u);   // RNE
    return (unsigned short)(u >> 16);
}

// fp32 -> bf16 elementwise, 8 elems/thread. n must be divisible by 8.
__global__ __launch_bounds__(256) void cvt_f32_bf16(
    const float* __restrict__ src, unsigned short* __restrict__ dst, int n)
{
    const int i = (blockIdx.x * 256 + threadIdx.x) * 8;
    if (i >= n) return;
    const float4 a = *(const float4*)(src + i);
    const float4 b = *(const float4*)(src + i + 4);
    ushortx8 o;
    o[0] = f2bf(a.x); o[1] = f2bf(a.y); o[2] = f2bf(a.z); o[3] = f2bf(a.w);
    o[4] = f2bf(b.x); o[5] = f2bf(b.y); o[6] = f2bf(b.z); o[7] = f2bf(b.w);
    *(ushortx8*)(dst + i) = o;
}

// C = A (M x K, row-major) * B^T (B is N x K, row-major). bf16 in, fp32 acc.
// MODE 0: output FP32, plain [M][N] to Cf.
// MODE 1: blockIdx.z selects (B0,C0)/(B1,C1)/(B2,C2); bf16 output head-major:
//         col n -> head h=n/64, C[h][m][n%64] with C shaped [NHEADS][M][64].
template <int MODE>
__global__ __launch_bounds__(256) void gemm_nt(
    const unsigned short* __restrict__ A,
    const unsigned short* __restrict__ B0,
    const unsigned short* __restrict__ B1,
    const unsigned short* __restrict__ B2,
    unsigned short* __restrict__ C0,
    unsigned short* __restrict__ C1,
    unsigned short* __restrict__ C2,
    float* __restrict__ Cf,
    int M, int N, int K)
{
    __shared__ __align__(16) unsigned short As[128 * 32];   // [row][k] 8KB
    __shared__ __align__(16) unsigned short Bs[128 * 32];   // [col][k] 8KB

    const int tid  = threadIdx.x;
    const int wave = tid >> 6;
    const int lane = tid & 63;
    const int quad = lane >> 4;
    const int l16  = lane & 15;
    const int wr   = wave >> 1;   // wave row (0..1) -> 64 rows each
    const int wc   = wave & 1;    // wave col (0..1) -> 64 cols each
    const int bm   = blockIdx.y * 128;
    const int bn   = blockIdx.x * 128;

    const unsigned short* B = B0;
    unsigned short* C = C0;
    if (MODE == 1) {
        if (blockIdx.z == 1)      { B = B1; C = C1; }
        else if (blockIdx.z == 2) { B = B2; C = C2; }
    }

    floatx4 acc[4][4];
    const floatx4 zf = {0.f, 0.f, 0.f, 0.f};
#pragma unroll
    for (int i = 0; i < 4; ++i)
#pragma unroll
        for (int j = 0; j < 4; ++j) acc[i][j] = zf;

    // Staging map: thread t covers row tid/2 (0..127), 16 k-elems at (tid&1)*16.
    const int srow = tid >> 1;
    const int scg  = (tid & 1) * 16;

    for (int kb = 0; kb < K; kb += 32) {
        __syncthreads();   // previous tile's fragment reads complete
        const unsigned short* ap = A + (size_t)(bm + srow) * K + kb + scg;
        const unsigned short* bp = B + (size_t)(bn + srow) * K + kb + scg;
        const ushortx8 a0 = *(const ushortx8*)ap;
        const ushortx8 a1 = *(const ushortx8*)(ap + 8);
        const ushortx8 b0 = *(const ushortx8*)bp;
        const ushortx8 b1 = *(const ushortx8*)(bp + 8);
        *(ushortx8*)&As[srow * 32 + scg]     = a0;
        *(ushortx8*)&As[srow * 32 + scg + 8] = a1;
        *(ushortx8*)&Bs[srow * 32 + scg]     = b0;
        *(ushortx8*)&Bs[srow * 32 + scg + 8] = b1;
        __syncthreads();   // LDS tiles ready

        bf16x8 af[4], bfr[4];
#pragma unroll
        for (int i = 0; i < 4; ++i) {
            af[i]  = *(const bf16x8*)&As[(wr * 64 + i * 16 + l16) * 32 + quad * 8];
            bfr[i] = *(const bf16x8*)&Bs[(wc * 64 + i * 16 + l16) * 32 + quad * 8];
        }
#pragma unroll
        for (int mi = 0; mi < 4; ++mi)
#pragma unroll
            for (int ni = 0; ni < 4; ++ni)
                acc[mi][ni] = __builtin_amdgcn_mfma_f32_16x16x32_bf16(af[mi], bfr[ni], acc[mi][ni], 0, 0, 0);
    }

    // Epilogue. C/D layout: col = lane&15, row = quad*4 + reg.
#pragma unroll
    for (int mi = 0; mi < 4; ++mi) {
#pragma unroll
        for (int ni = 0; ni < 4; ++ni) {
            const floatx4 v = acc[mi][ni];
#pragma unroll
            for (int r = 0; r < 4; ++r) {
                const int m = bm + wr * 64 + mi * 16 + quad * 4 + r;
                const int n = bn + wc * 64 + ni * 16 + l16;
                if (MODE == 0) {
                    Cf[(size_t)m * N + n] = v[r];
                } else {
                    const int h = n >> 6;
                    const int d = n & 63;
                    C[((size_t)h * M + m) * 64 + d] = f2bf(v[r]);
                }
            }
        }
    }
}

// Causal flash attention. Q/K/V: [H][S][64] bf16. Out: [S][768] bf16 at col h*64+d.
// Block: 256 thr = 4 waves; 64 Q rows per block (16 per wave); KV tiles of 64.
__global__ __launch_bounds__(256) void flash_attn(
    const unsigned short* __restrict__ Qh,
    const unsigned short* __restrict__ Kh,
    const unsigned short* __restrict__ Vh,
    unsigned short* __restrict__ Oout)
{
    __shared__ __align__(16) unsigned short Ks[64 * 64];      // [kv][d]  8KB
    __shared__ __align__(16) unsigned short Vs[64 * 64];      // [d][kv]  8KB (transposed)
    __shared__ __align__(16) unsigned short Ps[4][16 * 64];   // per-wave P staging, 8KB

    const int tid  = threadIdx.x;
    const int wave = tid >> 6;
    const int lane = tid & 63;
    const int quad = lane >> 4;
    const int l16  = lane & 15;
    const int h    = blockIdx.y;
    // heaviest (longest-KV) blocks first to reduce tail imbalance
    const int q0   = (int)(gridDim.x - 1 - blockIdx.x) * 64;

    const unsigned short* Qb = Qh + (size_t)h * S_LEN * 64;
    const unsigned short* Kb = Kh + (size_t)h * S_LEN * 64;
    const unsigned short* Vb = Vh + (size_t)h * S_LEN * 64;

    // Q fragments held in registers for whole block. A-layout: A[m=l16][k=quad*8+j].
    const int qrow = q0 + wave * 16 + l16;
    const bf16x8 qf0 = *(const bf16x8*)&Qb[(size_t)qrow * 64 + quad * 8];
    const bf16x8 qf1 = *(const bf16x8*)&Qb[(size_t)qrow * 64 + 32 + quad * 8];

    float m_i[4], l_i[4];
    floatx4 o[4];
    const floatx4 zf = {0.f, 0.f, 0.f, 0.f};
#pragma unroll
    for (int r = 0; r < 4; ++r) { m_i[r] = -1e30f; l_i[r] = 0.0f; }
#pragma unroll
    for (int d = 0; d < 4; ++d) o[d] = zf;

    // staging maps
    const int krow = tid >> 2;         // 0..63
    const int kcg  = (tid & 3) * 16;   // 0,16,32,48

    const int ntiles = q0 / 64 + 1;
    for (int t = 0; t < ntiles; ++t) {
        const int kv0 = t * 64;
        __syncthreads();   // previous tile's LDS reads complete

        // K tile: [kv][d], explicit 16-elem per thread
        {
            const unsigned short* kp = Kb + (size_t)(kv0 + krow) * 64 + kcg;
            const ushortx8 k0 = *(const ushortx8*)kp;
            const ushortx8 k1 = *(const ushortx8*)(kp + 8);
            *(ushortx8*)&Ks[krow * 64 + kcg]     = k0;
            *(ushortx8*)&Ks[krow * 64 + kcg + 8] = k1;
        }
        // V tile transposed into LDS: thread covers (row=tid/4, 16 d-elems)
        {
            const unsigned short* vp = Vb + (size_t)(kv0 + krow) * 64 + kcg;
            const ushortx8 v0 = *(const ushortx8*)vp;
            const ushortx8 v1 = *(const ushortx8*)(vp + 8);
#pragma unroll
            for (int i = 0; i < 8; ++i) Vs[(kcg + i) * 64 + krow] = v0[i];
#pragma unroll
            for (int i = 0; i < 8; ++i) Vs[(kcg + 8 + i) * 64 + krow] = v1[i];
        }
        __syncthreads();

        // S = Q K^T : per wave 16 q-rows x 64 keys, K=64 in two 32-chunks
        floatx4 s[4];
#pragma unroll
        for (int ns = 0; ns < 4; ++ns) s[ns] = zf;
#pragma unroll
        for (int ns = 0; ns < 4; ++ns) {
            const bf16x8 k0 = *(const bf16x8*)&Ks[(ns * 16 + l16) * 64 + quad * 8];
            const bf16x8 k1 = *(const bf16x8*)&Ks[(ns * 16 + l16) * 64 + 32 + quad * 8];
            s[ns] = __builtin_amdgcn_mfma_f32_16x16x32_bf16(qf0, k0, s[ns], 0, 0, 0);
            s[ns] = __builtin_amdgcn_mfma_f32_16x16x32_bf16(qf1, k1, s[ns], 0, 0, 0);
        }

        // scale + causal mask + per-row max (rows of this wave: quad*4+r)
        float sv[4][4];
        float mx[4] = {-3e38f, -3e38f, -3e38f, -3e38f};
#pragma unroll
        for (int ns = 0; ns < 4; ++ns) {
            const int kcol = kv0 + ns * 16 + l16;
#pragma unroll
            for (int r = 0; r < 4; ++r) {
                float v = s[ns][r] * 0.125f;
                const int qr = q0 + wave * 16 + quad * 4 + r;
                if (kcol > qr) v -= 1e9f;   // additive mask, matches reference
                sv[ns][r] = v;
                mx[r] = fmaxf(mx[r], v);
            }
        }
#pragma unroll
        for (int off = 8; off >= 1; off >>= 1)
#pragma unroll
            for (int r = 0; r < 4; ++r)
                mx[r] = fmaxf(mx[r], __shfl_xor(mx[r], off, 64));

        float al[4], rs[4];
#pragma unroll
        for (int r = 0; r < 4; ++r) {
            const float mn = fmaxf(m_i[r], mx[r]);
            al[r] = __expf(m_i[r] - mn);
            m_i[r] = mn;
            rs[r] = 0.f;
        }
        float pv[4][4];
#pragma unroll
        for (int ns = 0; ns < 4; ++ns)
#pragma unroll
            for (int r = 0; r < 4; ++r) {
                const float p = __expf(sv[ns][r] - m_i[r]);
                pv[ns][r] = p;
                rs[r] += p;
            }
#pragma unroll
        for (int off = 8; off >= 1; off >>= 1)
#pragma unroll
            for (int r = 0; r < 4; ++r)
                rs[r] += __shfl_xor(rs[r], off, 64);
#pragma unroll
        for (int r = 0; r < 4; ++r)
            l_i[r] = l_i[r] * al[r] + rs[r];
#pragma unroll
        for (int d = 0; d < 4; ++d)
#pragma unroll
            for (int r = 0; r < 4; ++r)
                o[d][r] = o[d][r] * al[r];

        // P: C-layout -> A-layout via per-wave LDS staging
#pragma unroll
        for (int ns = 0; ns < 4; ++ns)
#pragma unroll
            for (int r = 0; r < 4; ++r)
                Ps[wave][(quad * 4 + r) * 64 + ns * 16 + l16] = f2bf(pv[ns][r]);
        __syncthreads();

        const bf16x8 pf0 = *(const bf16x8*)&Ps[wave][l16 * 64 + quad * 8];
        const bf16x8 pf1 = *(const bf16x8*)&Ps[wave][l16 * 64 + 32 + quad * 8];
#pragma unroll
        for (int d = 0; d < 4; ++d) {
            const bf16x8 v0 = *(const bf16x8*)&Vs[(d * 16 + l16) * 64 + quad * 8];
            const bf16x8 v1 = *(const bf16x8*)&Vs[(d * 16 + l16) * 64 + 32 + quad * 8];
            o[d] = __builtin_amdgcn_mfma_f32_16x16x32_bf16(pf0, v0, o[d], 0, 0, 0);
            o[d] = __builtin_amdgcn_mfma_f32_16x16x32_bf16(pf1, v1, o[d], 0, 0, 0);
        }
    }

    // normalize and write attn_out [S][768] (col = h*64 + d)
#pragma unroll
    for (int d = 0; d < 4; ++d) {
#pragma unroll
        for (int r = 0; r < 4; ++r) {
            const int qr = q0 + wave * 16 + quad * 4 + r;
            const int dc = d * 16 + l16;
            Oout[(size_t)qr * DMODEL + h * 64 + dc] = f2bf(o[d][r] / l_i[r]);
        }
    }
}

extern "C" void kernel_launch(void* const* d_in, const int* in_sizes, int n_in,
                              void* d_out, int out_size, void* d_ws, size_t ws_size,
                              hipStream_t stream) {
    const float* x  = (const float*)d_in[0];
    const float* Wq = (const float*)d_in[1];
    const float* Wk = (const float*)d_in[2];
    const float* Wv = (const float*)d_in[3];
    const float* Wo = (const float*)d_in[4];

    const int xElems = S_LEN * DMODEL;          // 3,145,728
    const int wElems = DMODEL * DMODEL;         // 589,824
    const size_t headElems = (size_t)NHEADS * S_LEN * 64;   // 3,145,728

    unsigned short* xb  = (unsigned short*)d_ws;            // [4096][768]
    unsigned short* Wqb = xb  + xElems;
    unsigned short* Wkb = Wqb + wElems;
    unsigned short* Wvb = Wkb + wElems;
    unsigned short* Wob = Wvb + wElems;
    unsigned short* Qh  = Wob + wElems;                     // [12][4096][64]
    unsigned short* Kh  = Qh + headElems;
    unsigned short* Vh  = Kh + headElems;
    unsigned short* AO  = Vh + headElems;                   // [4096][768] bf16

    // 0) fp32 -> bf16 conversions
    cvt_f32_bf16<<<dim3(xElems / 2048), dim3(256), 0, stream>>>(x,  xb,  xElems);
    cvt_f32_bf16<<<dim3(wElems / 2048), dim3(256), 0, stream>>>(Wq, Wqb, wElems);
    cvt_f32_bf16<<<dim3(wElems / 2048), dim3(256), 0, stream>>>(Wk, Wkb, wElems);
    cvt_f32_bf16<<<dim3(wElems / 2048), dim3(256), 0, stream>>>(Wv, Wvb, wElems);
    cvt_f32_bf16<<<dim3(wElems / 2048), dim3(256), 0, stream>>>(Wo, Wob, wElems);

    // 1) QKV projections
    gemm_nt<1><<<dim3(DMODEL / 128, S_LEN / 128, 3), dim3(256), 0, stream>>>(
        xb, Wqb, Wkb, Wvb, Qh, Kh, Vh, nullptr, S_LEN, DMODEL, DMODEL);

    // 2) causal flash attention
    flash_attn<<<dim3(S_LEN / 64, NHEADS), dim3(256), 0, stream>>>(Qh, Kh, Vh, AO);

    // 3) output projection -> fp32 d_out
    gemm_nt<0><<<dim3(DMODEL / 128, S_LEN / 128, 1), dim3(256), 0, stream>>>(
        AO, Wob, nullptr, nullptr, nullptr, nullptr, nullptr,
        (float*)d_out, S_LEN, DMODEL, DMODEL);
}

// Round 4
// 258.693 us; speedup vs baseline: 1.5493x; 1.5493x over previous
//
#include <hip/hip_runtime.h>
#include <hip/hip_bf16.h>
#include <stdint.h>

// MultiHeadSelfAttention, B=1, S=4096, D_MODEL=768, H=12, Dk=64, causal.
// FP32 I/O, bf16 MFMA inside. Launches:
//   0) cvt_all: x,Wq,Wk,Wv,Wo fp32->bf16 (one fused kernel)
//   1) gemm_nt<1>: QKV projections -> [H][S][64] bf16
//   2) flash_part: causal flash attention, KV split in 1024-chunks; single-chunk
//      q-blocks write AO directly, multi-chunk write (m,l,O) partials
//   3) combine: merge chunk partials -> AO
//   4) gemm_nt<0>: AO @ Wo^T -> d_out fp32
// R3: LDS strides padded 64->72 elems (kills 16-way b128 fragment-read conflicts),
//     KV-chunk split for work balance (768 blocks x 1..64 tiles -> 1920 x <=16).

#define S_LEN  4096
#define DMODEL 768
#define NHEADS 12
#define LDSW   72          // padded LDS row stride (elems); 144B = 16B-aligned
#define CHUNK  1024        // kv elems per flash work item (16 tiles)
#define WPH    160         // work items per head: 64 + 48 + 32 + 16

typedef __attribute__((ext_vector_type(8))) __bf16 bf16x8;
typedef __attribute__((ext_vector_type(8))) unsigned short ushortx8;
typedef __attribute__((ext_vector_type(4))) float floatx4;

__device__ __forceinline__ unsigned short f2bf(float f) {
    unsigned int u = __float_as_uint(f);
    u += 0x7fffu + ((u >> 16) & 1u);   // RNE
    return (unsigned short)(u >> 16);
}
__device__ __forceinline__ float bf2f(unsigned short v) {
    return __uint_as_float(((unsigned int)v) << 16);
}

// ---------------- fused fp32->bf16 conversion ----------------
// blocks: [0,1536) x | +288 Wq | +288 Wk | +288 Wv | +288 Wo   (2048 elems/block)
__global__ __launch_bounds__(256) void cvt_all(
    const float* __restrict__ x,  const float* __restrict__ Wq,
    const float* __restrict__ Wk, const float* __restrict__ Wv,
    const float* __restrict__ Wo,
    unsigned short* __restrict__ xb,  unsigned short* __restrict__ Wqb,
    unsigned short* __restrict__ Wkb, unsigned short* __restrict__ Wvb,
    unsigned short* __restrict__ Wob)
{
    int b = blockIdx.x;
    const float* src; unsigned short* dst;
    if (b < 1536)      { src = x;  dst = xb;  }
    else if (b < 1824) { src = Wq; dst = Wqb; b -= 1536; }
    else if (b < 2112) { src = Wk; dst = Wkb; b -= 1824; }
    else if (b < 2400) { src = Wv; dst = Wvb; b -= 2112; }
    else               { src = Wo; dst = Wob; b -= 2400; }
    const int i = (b * 256 + threadIdx.x) * 8;
    const float4 a0 = *(const float4*)(src + i);
    const float4 a1 = *(const float4*)(src + i + 4);
    ushortx8 o;
    o[0] = f2bf(a0.x); o[1] = f2bf(a0.y); o[2] = f2bf(a0.z); o[3] = f2bf(a0.w);
    o[4] = f2bf(a1.x); o[5] = f2bf(a1.y); o[6] = f2bf(a1.z); o[7] = f2bf(a1.w);
    *(ushortx8*)(dst + i) = o;
}

// ---------------- GEMM C = A * B^T ----------------
template <int MODE>
__global__ __launch_bounds__(256) void gemm_nt(
    const unsigned short* __restrict__ A,
    const unsigned short* __restrict__ B0,
    const unsigned short* __restrict__ B1,
    const unsigned short* __restrict__ B2,
    unsigned short* __restrict__ C0,
    unsigned short* __restrict__ C1,
    unsigned short* __restrict__ C2,
    float* __restrict__ Cf,
    int M, int N, int K)
{
    __shared__ __align__(16) unsigned short As[128 * 32];
    __shared__ __align__(16) unsigned short Bs[128 * 32];

    const int tid  = threadIdx.x;
    const int wave = tid >> 6;
    const int lane = tid & 63;
    const int quad = lane >> 4;
    const int l16  = lane & 15;
    const int wr   = wave >> 1;
    const int wc   = wave & 1;
    const int bm   = blockIdx.y * 128;
    const int bn   = blockIdx.x * 128;

    const unsigned short* B = B0;
    unsigned short* C = C0;
    if (MODE == 1) {
        if (blockIdx.z == 1)      { B = B1; C = C1; }
        else if (blockIdx.z == 2) { B = B2; C = C2; }
    }

    floatx4 acc[4][4];
    const floatx4 zf = {0.f, 0.f, 0.f, 0.f};
#pragma unroll
    for (int i = 0; i < 4; ++i)
#pragma unroll
        for (int j = 0; j < 4; ++j) acc[i][j] = zf;

    const int srow = tid >> 1;
    const int scg  = (tid & 1) * 16;

    for (int kb = 0; kb < K; kb += 32) {
        __syncthreads();
        const unsigned short* ap = A + (size_t)(bm + srow) * K + kb + scg;
        const unsigned short* bp = B + (size_t)(bn + srow) * K + kb + scg;
        const ushortx8 a0 = *(const ushortx8*)ap;
        const ushortx8 a1 = *(const ushortx8*)(ap + 8);
        const ushortx8 b0 = *(const ushortx8*)bp;
        const ushortx8 b1 = *(const ushortx8*)(bp + 8);
        *(ushortx8*)&As[srow * 32 + scg]     = a0;
        *(ushortx8*)&As[srow * 32 + scg + 8] = a1;
        *(ushortx8*)&Bs[srow * 32 + scg]     = b0;
        *(ushortx8*)&Bs[srow * 32 + scg + 8] = b1;
        __syncthreads();

        bf16x8 af[4], bfr[4];
#pragma unroll
        for (int i = 0; i < 4; ++i) {
            af[i]  = *(const bf16x8*)&As[(wr * 64 + i * 16 + l16) * 32 + quad * 8];
            bfr[i] = *(const bf16x8*)&Bs[(wc * 64 + i * 16 + l16) * 32 + quad * 8];
        }
#pragma unroll
        for (int mi = 0; mi < 4; ++mi)
#pragma unroll
            for (int ni = 0; ni < 4; ++ni)
                acc[mi][ni] = __builtin_amdgcn_mfma_f32_16x16x32_bf16(af[mi], bfr[ni], acc[mi][ni], 0, 0, 0);
    }

#pragma unroll
    for (int mi = 0; mi < 4; ++mi) {
#pragma unroll
        for (int ni = 0; ni < 4; ++ni) {
            const floatx4 v = acc[mi][ni];
#pragma unroll
            for (int r = 0; r < 4; ++r) {
                const int m = bm + wr * 64 + mi * 16 + quad * 4 + r;
                const int n = bn + wc * 64 + ni * 16 + l16;
                if (MODE == 0) {
                    Cf[(size_t)m * N + n] = v[r];
                } else {
                    const int h = n >> 6;
                    const int d = n & 63;
                    C[((size_t)h * M + m) * 64 + d] = f2bf(v[r]);
                }
            }
        }
    }
}

// ---------------- flash attention, KV-chunked ----------------
// grid (WPH, NHEADS). Work item w -> (chunk c, q-block qb):
//   w<64: c=0,qb=w | w<112: c=1,qb=16+(w-64) | w<144: c=2,qb=32+(w-112) | else c=3,qb=48+(w-144)
// qb<16 (single chunk): write normalized O to AO. Else: write partials Opart/ml.
__global__ __launch_bounds__(256) void flash_part(
    const unsigned short* __restrict__ Qh,
    const unsigned short* __restrict__ Kh,
    const unsigned short* __restrict__ Vh,
    unsigned short* __restrict__ AO,       // [S][768] bf16
    unsigned short* __restrict__ Opart,    // [NHEADS*WPH][64*64] bf16 (unnormalized)
    float* __restrict__ ml)                // [NHEADS*WPH][64*2] fp32 (m,l)
{
    __shared__ __align__(16) unsigned short Ks[64 * LDSW];
    __shared__ __align__(16) unsigned short Vs[64 * LDSW];       // [d][kv]
    __shared__ __align__(16) unsigned short Ps[4][16 * LDSW];

    const int tid  = threadIdx.x;
    const int wave = tid >> 6;
    const int lane = tid & 63;
    const int quad = lane >> 4;
    const int l16  = lane & 15;
    const int h    = blockIdx.y;
    const int w    = blockIdx.x;

    int c, qb;
    if (w < 64)       { c = 0; qb = w; }
    else if (w < 112) { c = 1; qb = 16 + (w - 64); }
    else if (w < 144) { c = 2; qb = 32 + (w - 112); }
    else              { c = 3; qb = 48 + (w - 144); }

    const int q0       = qb * 64;
    const int kv_start = c * CHUNK;
    const int kv_end   = min(kv_start + CHUNK, q0 + 64);
    const int ntiles   = (kv_end - kv_start) >> 6;

    const unsigned short* Qb = Qh + (size_t)h * S_LEN * 64;
    const unsigned short* Kb = Kh + (size_t)h * S_LEN * 64;
    const unsigned short* Vb = Vh + (size_t)h * S_LEN * 64;

    // Q fragments (A-layout) for the whole block
    const int qrow = q0 + wave * 16 + l16;
    const bf16x8 qf0 = *(const bf16x8*)&Qb[(size_t)qrow * 64 + quad * 8];
    const bf16x8 qf1 = *(const bf16x8*)&Qb[(size_t)qrow * 64 + 32 + quad * 8];

    float m_i[4], l_i[4];
    floatx4 o[4];
    const floatx4 zf = {0.f, 0.f, 0.f, 0.f};
#pragma unroll
    for (int r = 0; r < 4; ++r) { m_i[r] = -1e30f; l_i[r] = 0.0f; }
#pragma unroll
    for (int d = 0; d < 4; ++d) o[d] = zf;

    // staging maps
    const int krow = tid >> 2;           // K: row 0..63
    const int kcg  = (tid & 3) * 16;     // K: 16 d-elems
    const int vrow = tid & 63;           // V: kv row (per chunk)
    const int vdc  = tid >> 6;           // V: d-chunk 0..3 (and +4)

    for (int t = 0; t < ntiles; ++t) {
        const int kv0 = kv_start + t * 64;
        __syncthreads();

        // K tile [kv][d] -> Ks stride LDSW
        {
            const unsigned short* kp = Kb + (size_t)(kv0 + krow) * 64 + kcg;
            const ushortx8 k0 = *(const ushortx8*)kp;
            const ushortx8 k1 = *(const ushortx8*)(kp + 8);
            *(ushortx8*)&Ks[krow * LDSW + kcg]     = k0;
            *(ushortx8*)&Ks[krow * LDSW + kcg + 8] = k1;
        }
        // V tile transposed -> Vs[d][kv]; each instr spans 64 kv rows -> 2-way banks
#pragma unroll
        for (int half = 0; half < 2; ++half) {
            const int dc = vdc + half * 4;
            const ushortx8 v = *(const ushortx8*)(Vb + (size_t)(kv0 + vrow) * 64 + dc * 8);
#pragma unroll
            for (int i = 0; i < 8; ++i) Vs[(dc * 8 + i) * LDSW + vrow] = v[i];
        }
        __syncthreads();

        // S = Q K^T
        floatx4 s[4];
#pragma unroll
        for (int ns = 0; ns < 4; ++ns) s[ns] = zf;
#pragma unroll
        for (int ns = 0; ns < 4; ++ns) {
            const bf16x8 k0 = *(const bf16x8*)&Ks[(ns * 16 + l16) * LDSW + quad * 8];
            const bf16x8 k1 = *(const bf16x8*)&Ks[(ns * 16 + l16) * LDSW + 32 + quad * 8];
            s[ns] = __builtin_amdgcn_mfma_f32_16x16x32_bf16(qf0, k0, s[ns], 0, 0, 0);
            s[ns] = __builtin_amdgcn_mfma_f32_16x16x32_bf16(qf1, k1, s[ns], 0, 0, 0);
        }

        // scale + causal mask + row max
        float sv[4][4];
        float mx[4] = {-3e38f, -3e38f, -3e38f, -3e38f};
#pragma unroll
        for (int ns = 0; ns < 4; ++ns) {
            const int kcol = kv0 + ns * 16 + l16;
#pragma unroll
            for (int r = 0; r < 4; ++r) {
                float v = s[ns][r] * 0.125f;
                const int qr = q0 + wave * 16 + quad * 4 + r;
                if (kcol > qr) v -= 1e9f;
                sv[ns][r] = v;
                mx[r] = fmaxf(mx[r], v);
            }
        }
#pragma unroll
        for (int off = 8; off >= 1; off >>= 1)
#pragma unroll
            for (int r = 0; r < 4; ++r)
                mx[r] = fmaxf(mx[r], __shfl_xor(mx[r], off, 64));

        float al[4], rs[4];
#pragma unroll
        for (int r = 0; r < 4; ++r) {
            const float mn = fmaxf(m_i[r], mx[r]);
            al[r] = __expf(m_i[r] - mn);
            m_i[r] = mn;
            rs[r] = 0.f;
        }
        float pv[4][4];
#pragma unroll
        for (int ns = 0; ns < 4; ++ns)
#pragma unroll
            for (int r = 0; r < 4; ++r) {
                const float p = __expf(sv[ns][r] - m_i[r]);
                pv[ns][r] = p;
                rs[r] += p;
            }
#pragma unroll
        for (int off = 8; off >= 1; off >>= 1)
#pragma unroll
            for (int r = 0; r < 4; ++r)
                rs[r] += __shfl_xor(rs[r], off, 64);
#pragma unroll
        for (int r = 0; r < 4; ++r)
            l_i[r] = l_i[r] * al[r] + rs[r];
#pragma unroll
        for (int d = 0; d < 4; ++d)
#pragma unroll
            for (int r = 0; r < 4; ++r)
                o[d][r] = o[d][r] * al[r];

        // P: C-layout -> A-layout via per-wave LDS
#pragma unroll
        for (int ns = 0; ns < 4; ++ns)
#pragma unroll
            for (int r = 0; r < 4; ++r)
                Ps[wave][(quad * 4 + r) * LDSW + ns * 16 + l16] = f2bf(pv[ns][r]);
        __syncthreads();

        const bf16x8 pf0 = *(const bf16x8*)&Ps[wave][l16 * LDSW + quad * 8];
        const bf16x8 pf1 = *(const bf16x8*)&Ps[wave][l16 * LDSW + 32 + quad * 8];
#pragma unroll
        for (int d = 0; d < 4; ++d) {
            const bf16x8 v0 = *(const bf16x8*)&Vs[(d * 16 + l16) * LDSW + quad * 8];
            const bf16x8 v1 = *(const bf16x8*)&Vs[(d * 16 + l16) * LDSW + 32 + quad * 8];
            o[d] = __builtin_amdgcn_mfma_f32_16x16x32_bf16(pf0, v0, o[d], 0, 0, 0);
            o[d] = __builtin_amdgcn_mfma_f32_16x16x32_bf16(pf1, v1, o[d], 0, 0, 0);
        }
    }

    if (qb < 16) {
        // single-chunk: normalized write to AO
#pragma unroll
        for (int d = 0; d < 4; ++d)
#pragma unroll
            for (int r = 0; r < 4; ++r) {
                const int qr = q0 + wave * 16 + quad * 4 + r;
                AO[(size_t)qr * DMODEL + h * 64 + d * 16 + l16] = f2bf(o[d][r] / l_i[r]);
            }
    } else {
        const int slot = h * WPH + w;
        unsigned short* op = Opart + (size_t)slot * 4096;
#pragma unroll
        for (int d = 0; d < 4; ++d)
#pragma unroll
            for (int r = 0; r < 4; ++r)
                op[(wave * 16 + quad * 4 + r) * 64 + d * 16 + l16] = f2bf(o[d][r]);
        if (l16 == 0) {
            float* mlp = ml + (size_t)slot * 128;
#pragma unroll
            for (int r = 0; r < 4; ++r) {
                const int row = wave * 16 + quad * 4 + r;
                mlp[row * 2]     = m_i[r];
                mlp[row * 2 + 1] = l_i[r];
            }
        }
    }
}

// ---------------- combine chunk partials ----------------
// grid (48, 12): qb = 16+x, h = y. thread: row=tid>>2, 16 d at (tid&3)*16.
__global__ __launch_bounds__(256) void combine(
    const unsigned short* __restrict__ Opart,
    const float* __restrict__ ml,
    unsigned short* __restrict__ AO)
{
    const int qb  = 16 + blockIdx.x;
    const int h   = blockIdx.y;
    const int row = threadIdx.x >> 2;
    const int ds  = (threadIdx.x & 3) * 16;
    const int nc  = (qb >> 4) + 1;

    int wslot[4];
    wslot[0] = qb;
    wslot[1] = 64 + qb - 16;
    wslot[2] = 112 + qb - 32;
    wslot[3] = 144 + qb - 48;

    float mc[4], lc[4];
    float M = -3e38f;
    for (int cI = 0; cI < nc; ++cI) {
        const int slot = h * WPH + wslot[cI];
        mc[cI] = ml[(size_t)slot * 128 + row * 2];
        lc[cI] = ml[(size_t)slot * 128 + row * 2 + 1];
        M = fmaxf(M, mc[cI]);
    }
    float L = 0.f;
    float acc[16];
#pragma unroll
    for (int i = 0; i < 16; ++i) acc[i] = 0.f;

    for (int cI = 0; cI < nc; ++cI) {
        const float sc = __expf(mc[cI] - M);
        L += sc * lc[cI];
        const int slot = h * WPH + wslot[cI];
        const unsigned short* op = Opart + (size_t)slot * 4096 + row * 64 + ds;
        const ushortx8 a = *(const ushortx8*)op;
        const ushortx8 b = *(const ushortx8*)(op + 8);
#pragma unroll
        for (int i = 0; i < 8; ++i) acc[i]     += sc * bf2f(a[i]);
#pragma unroll
        for (int i = 0; i < 8; ++i) acc[8 + i] += sc * bf2f(b[i]);
    }
    const float inv = 1.0f / L;
    ushortx8 o0, o1;
#pragma unroll
    for (int i = 0; i < 8; ++i) { o0[i] = f2bf(acc[i] * inv); o1[i] = f2bf(acc[8 + i] * inv); }
    unsigned short* dst = AO + (size_t)(qb * 64 + row) * DMODEL + h * 64 + ds;
    *(ushortx8*)dst = o0;
    *(ushortx8*)(dst + 8) = o1;
}

extern "C" void kernel_launch(void* const* d_in, const int* in_sizes, int n_in,
                              void* d_out, int out_size, void* d_ws, size_t ws_size,
                              hipStream_t stream) {
    const float* x  = (const float*)d_in[0];
    const float* Wq = (const float*)d_in[1];
    const float* Wk = (const float*)d_in[2];
    const float* Wv = (const float*)d_in[3];
    const float* Wo = (const float*)d_in[4];

    const int xElems = S_LEN * DMODEL;
    const int wElems = DMODEL * DMODEL;
    const size_t headElems = (size_t)NHEADS * S_LEN * 64;
    const int nslots = NHEADS * WPH;   // 1920

    unsigned short* xb  = (unsigned short*)d_ws;
    unsigned short* Wqb = xb  + xElems;
    unsigned short* Wkb = Wqb + wElems;
    unsigned short* Wvb = Wkb + wElems;
    unsigned short* Wob = Wvb + wElems;
    unsigned short* Qh  = Wob + wElems;
    unsigned short* Kh  = Qh + headElems;
    unsigned short* Vh  = Kh + headElems;
    unsigned short* AO  = Vh + headElems;
    unsigned short* Opart = AO + xElems;                 // [1920][4096] bf16
    float* ml = (float*)(Opart + (size_t)nslots * 4096); // [1920][128] fp32

    cvt_all<<<dim3(2688), dim3(256), 0, stream>>>(x, Wq, Wk, Wv, Wo,
                                                  xb, Wqb, Wkb, Wvb, Wob);

    gemm_nt<1><<<dim3(DMODEL / 128, S_LEN / 128, 3), dim3(256), 0, stream>>>(
        xb, Wqb, Wkb, Wvb, Qh, Kh, Vh, nullptr, S_LEN, DMODEL, DMODEL);

    flash_part<<<dim3(WPH, NHEADS), dim3(256), 0, stream>>>(Qh, Kh, Vh, AO, Opart, ml);

    combine<<<dim3(48, NHEADS), dim3(256), 0, stream>>>(Opart, ml, AO);

    gemm_nt<0><<<dim3(DMODEL / 128, S_LEN / 128, 1), dim3(256), 0, stream>>>(
        AO, Wob, nullptr, nullptr, nullptr, nullptr, nullptr,
        (float*)d_out, S_LEN, DMODEL, DMODEL);
}

// Round 5
// 240.643 us; speedup vs baseline: 1.6655x; 1.0750x over previous
//
#include <hip/hip_runtime.h>
#include <hip/hip_bf16.h>
#include <stdint.h>

// MultiHeadSelfAttention, B=1, S=4096, D_MODEL=768, H=12, Dk=64, causal.
// FP32 I/O, bf16 MFMA inside. Launches:
//   0) cvt_all    fp32->bf16
//   1) gemm_nt<1> QKV projections -> [H][S][64] bf16
//   2) flash_part causal flash attention (Q-tile 128, KV chunks of 1024,
//                 double-buffered K/V LDS, 1 barrier/tile)
//   3) combine    merge chunk partials -> AO
//   4) gemm_nt<0> AO @ Wo^T -> d_out fp32
// R4: flash Q-tile 64->128 (8 waves), K/V double-buffer + reg prefetch,
//     removed Ps barrier (per-wave region), mask-skip on non-diagonal tiles.

#define S_LEN  4096
#define DMODEL 768
#define NHEADS 12
#define LDSW   72          // padded LDS row stride (elems)
#define WPH    80          // work items per head: 32 + 24 + 16 + 8 (chunks of 1024 kv)

typedef __attribute__((ext_vector_type(8))) __bf16 bf16x8;
typedef __attribute__((ext_vector_type(8))) unsigned short ushortx8;
typedef __attribute__((ext_vector_type(4))) float floatx4;

__device__ __forceinline__ unsigned short f2bf(float f) {
    unsigned int u = __float_as_uint(f);
    u += 0x7fffu + ((u >> 16) & 1u);   // RNE
    return (unsigned short)(u >> 16);
}
__device__ __forceinline__ float bf2f(unsigned short v) {
    return __uint_as_float(((unsigned int)v) << 16);
}

// ---------------- fused fp32->bf16 conversion ----------------
__global__ __launch_bounds__(256) void cvt_all(
    const float* __restrict__ x,  const float* __restrict__ Wq,
    const float* __restrict__ Wk, const float* __restrict__ Wv,
    const float* __restrict__ Wo,
    unsigned short* __restrict__ xb,  unsigned short* __restrict__ Wqb,
    unsigned short* __restrict__ Wkb, unsigned short* __restrict__ Wvb,
    unsigned short* __restrict__ Wob)
{
    int b = blockIdx.x;
    const float* src; unsigned short* dst;
    if (b < 1536)      { src = x;  dst = xb;  }
    else if (b < 1824) { src = Wq; dst = Wqb; b -= 1536; }
    else if (b < 2112) { src = Wk; dst = Wkb; b -= 1824; }
    else if (b < 2400) { src = Wv; dst = Wvb; b -= 2112; }
    else               { src = Wo; dst = Wob; b -= 2400; }
    const int i = (b * 256 + threadIdx.x) * 8;
    const float4 a0 = *(const float4*)(src + i);
    const float4 a1 = *(const float4*)(src + i + 4);
    ushortx8 o;
    o[0] = f2bf(a0.x); o[1] = f2bf(a0.y); o[2] = f2bf(a0.z); o[3] = f2bf(a0.w);
    o[4] = f2bf(a1.x); o[5] = f2bf(a1.y); o[6] = f2bf(a1.z); o[7] = f2bf(a1.w);
    *(ushortx8*)(dst + i) = o;
}

// ---------------- GEMM C = A * B^T ----------------
template <int MODE>
__global__ __launch_bounds__(256) void gemm_nt(
    const unsigned short* __restrict__ A,
    const unsigned short* __restrict__ B0,
    const unsigned short* __restrict__ B1,
    const unsigned short* __restrict__ B2,
    unsigned short* __restrict__ C0,
    unsigned short* __restrict__ C1,
    unsigned short* __restrict__ C2,
    float* __restrict__ Cf,
    int M, int N, int K)
{
    __shared__ __align__(16) unsigned short As[128 * 32];
    __shared__ __align__(16) unsigned short Bs[128 * 32];

    const int tid  = threadIdx.x;
    const int wave = tid >> 6;
    const int lane = tid & 63;
    const int quad = lane >> 4;
    const int l16  = lane & 15;
    const int wr   = wave >> 1;
    const int wc   = wave & 1;
    const int bm   = blockIdx.y * 128;
    const int bn   = blockIdx.x * 128;

    const unsigned short* B = B0;
    unsigned short* C = C0;
    if (MODE == 1) {
        if (blockIdx.z == 1)      { B = B1; C = C1; }
        else if (blockIdx.z == 2) { B = B2; C = C2; }
    }

    floatx4 acc[4][4];
    const floatx4 zf = {0.f, 0.f, 0.f, 0.f};
#pragma unroll
    for (int i = 0; i < 4; ++i)
#pragma unroll
        for (int j = 0; j < 4; ++j) acc[i][j] = zf;

    const int srow = tid >> 1;
    const int scg  = (tid & 1) * 16;

    for (int kb = 0; kb < K; kb += 32) {
        __syncthreads();
        const unsigned short* ap = A + (size_t)(bm + srow) * K + kb + scg;
        const unsigned short* bp = B + (size_t)(bn + srow) * K + kb + scg;
        const ushortx8 a0 = *(const ushortx8*)ap;
        const ushortx8 a1 = *(const ushortx8*)(ap + 8);
        const ushortx8 b0 = *(const ushortx8*)bp;
        const ushortx8 b1 = *(const ushortx8*)(bp + 8);
        *(ushortx8*)&As[srow * 32 + scg]     = a0;
        *(ushortx8*)&As[srow * 32 + scg + 8] = a1;
        *(ushortx8*)&Bs[srow * 32 + scg]     = b0;
        *(ushortx8*)&Bs[srow * 32 + scg + 8] = b1;
        __syncthreads();

        bf16x8 af[4], bfr[4];
#pragma unroll
        for (int i = 0; i < 4; ++i) {
            af[i]  = *(const bf16x8*)&As[(wr * 64 + i * 16 + l16) * 32 + quad * 8];
            bfr[i] = *(const bf16x8*)&Bs[(wc * 64 + i * 16 + l16) * 32 + quad * 8];
        }
#pragma unroll
        for (int mi = 0; mi < 4; ++mi)
#pragma unroll
            for (int ni = 0; ni < 4; ++ni)
                acc[mi][ni] = __builtin_amdgcn_mfma_f32_16x16x32_bf16(af[mi], bfr[ni], acc[mi][ni], 0, 0, 0);
    }

#pragma unroll
    for (int mi = 0; mi < 4; ++mi) {
#pragma unroll
        for (int ni = 0; ni < 4; ++ni) {
            const floatx4 v = acc[mi][ni];
#pragma unroll
            for (int r = 0; r < 4; ++r) {
                const int m = bm + wr * 64 + mi * 16 + quad * 4 + r;
                const int n = bn + wc * 64 + ni * 16 + l16;
                if (MODE == 0) {
                    Cf[(size_t)m * N + n] = v[r];
                } else {
                    const int h = n >> 6;
                    const int d = n & 63;
                    C[((size_t)h * M + m) * 64 + d] = f2bf(v[r]);
                }
            }
        }
    }
}

// ---------------- flash attention: Q-tile 128, KV chunks of 1024 ----------------
// grid (WPH, NHEADS), 512 threads = 8 waves (16 q rows each).
// item w -> (chunk c, q-block qb[128 rows]):
//   w<32: c=0,qb=w | w<56: c=1,qb=8+(w-32) | w<72: c=2,qb=16+(w-56) | else c=3,qb=24+(w-72)
// qb<8 (single chunk): normalized write to AO. Else partials Opart [slot][128*64] + ml.
__global__ __launch_bounds__(512) void flash_part(
    const unsigned short* __restrict__ Qh,
    const unsigned short* __restrict__ Kh,
    const unsigned short* __restrict__ Vh,
    unsigned short* __restrict__ AO,
    unsigned short* __restrict__ Opart,
    float* __restrict__ ml)
{
    __shared__ __align__(16) unsigned short Ks[2][64 * LDSW];
    __shared__ __align__(16) unsigned short Vs[2][64 * LDSW];     // [d][kv]
    __shared__ __align__(16) unsigned short Ps[8][16 * LDSW];

    const int tid  = threadIdx.x;
    const int wave = tid >> 6;
    const int lane = tid & 63;
    const int quad = lane >> 4;
    const int l16  = lane & 15;
    const int h    = blockIdx.y;
    const int w    = blockIdx.x;

    int c, qb;
    if (w < 32)      { c = 0; qb = w; }
    else if (w < 56) { c = 1; qb = 8  + (w - 32); }
    else if (w < 72) { c = 2; qb = 16 + (w - 56); }
    else             { c = 3; qb = 24 + (w - 72); }

    const int q0       = qb * 128;
    const int kv_start = c * 1024;
    const int kv_end   = min(kv_start + 1024, q0 + 128);
    const int ntiles   = (kv_end - kv_start) >> 6;   // >= 2 always

    const unsigned short* Qb = Qh + (size_t)h * S_LEN * 64;
    const unsigned short* Kb = Kh + (size_t)h * S_LEN * 64;
    const unsigned short* Vb = Vh + (size_t)h * S_LEN * 64;

    // Q fragments (A-layout), 16 rows per wave
    const int qminw = q0 + wave * 16;
    const int qrow  = qminw + l16;
    const bf16x8 qf0 = *(const bf16x8*)&Qb[(size_t)qrow * 64 + quad * 8];
    const bf16x8 qf1 = *(const bf16x8*)&Qb[(size_t)qrow * 64 + 32 + quad * 8];

    float m_i[4], l_i[4];
    floatx4 o[4];
    const floatx4 zf = {0.f, 0.f, 0.f, 0.f};
#pragma unroll
    for (int r = 0; r < 4; ++r) { m_i[r] = -1e30f; l_i[r] = 0.0f; }
#pragma unroll
    for (int d = 0; d < 4; ++d) o[d] = zf;

    // staging maps (512 threads)
    const int krow = tid >> 3;          // 0..63
    const int kc   = (tid & 7) * 8;     // 8 d-elems
    const int vrow = tid & 63;          // kv row
    const int vdc  = tid >> 6;          // d-chunk 0..7

    // prologue: stage tile 0 into buf 0
    {
        const ushortx8 k0 = *(const ushortx8*)(Kb + (size_t)(kv_start + krow) * 64 + kc);
        const ushortx8 v0 = *(const ushortx8*)(Vb + (size_t)(kv_start + vrow) * 64 + vdc * 8);
        *(ushortx8*)&Ks[0][krow * LDSW + kc] = k0;
#pragma unroll
        for (int i = 0; i < 8; ++i) Vs[0][(vdc * 8 + i) * LDSW + vrow] = v0[i];
    }
    __syncthreads();

    for (int t = 0; t < ntiles; ++t) {
        const int buf = t & 1;
        const int kv0 = kv_start + t * 64;
        const bool pre = (t + 1 < ntiles);

        ushortx8 kreg, vreg;
        if (pre) {   // prefetch tile t+1 into registers (hidden behind compute)
            kreg = *(const ushortx8*)(Kb + (size_t)(kv0 + 64 + krow) * 64 + kc);
            vreg = *(const ushortx8*)(Vb + (size_t)(kv0 + 64 + vrow) * 64 + vdc * 8);
        }

        if (kv0 <= qminw + 15) {   // skip fully-masked tiles for this wave
            // S = Q K^T
            floatx4 s[4];
#pragma unroll
            for (int ns = 0; ns < 4; ++ns) s[ns] = zf;
#pragma unroll
            for (int ns = 0; ns < 4; ++ns) {
                const bf16x8 k0 = *(const bf16x8*)&Ks[buf][(ns * 16 + l16) * LDSW + quad * 8];
                const bf16x8 k1 = *(const bf16x8*)&Ks[buf][(ns * 16 + l16) * LDSW + 32 + quad * 8];
                s[ns] = __builtin_amdgcn_mfma_f32_16x16x32_bf16(qf0, k0, s[ns], 0, 0, 0);
                s[ns] = __builtin_amdgcn_mfma_f32_16x16x32_bf16(qf1, k1, s[ns], 0, 0, 0);
            }

            float sv[4][4];
            float mx[4] = {-3e38f, -3e38f, -3e38f, -3e38f};
            if (kv0 + 63 > qminw) {   // diagonal tile: apply causal mask
#pragma unroll
                for (int ns = 0; ns < 4; ++ns) {
                    const int kcol = kv0 + ns * 16 + l16;
#pragma unroll
                    for (int r = 0; r < 4; ++r) {
                        float v = s[ns][r] * 0.125f;
                        if (kcol > qminw + quad * 4 + r) v -= 1e9f;
                        sv[ns][r] = v;
                        mx[r] = fmaxf(mx[r], v);
                    }
                }
            } else {                  // interior tile: no mask
#pragma unroll
                for (int ns = 0; ns < 4; ++ns)
#pragma unroll
                    for (int r = 0; r < 4; ++r) {
                        const float v = s[ns][r] * 0.125f;
                        sv[ns][r] = v;
                        mx[r] = fmaxf(mx[r], v);
                    }
            }
#pragma unroll
            for (int off = 8; off >= 1; off >>= 1)
#pragma unroll
                for (int r = 0; r < 4; ++r)
                    mx[r] = fmaxf(mx[r], __shfl_xor(mx[r], off, 64));

            float al[4], rs[4];
#pragma unroll
            for (int r = 0; r < 4; ++r) {
                const float mn = fmaxf(m_i[r], mx[r]);
                al[r] = __expf(m_i[r] - mn);
                m_i[r] = mn;
                rs[r] = 0.f;
            }
            float pv[4][4];
#pragma unroll
            for (int ns = 0; ns < 4; ++ns)
#pragma unroll
                for (int r = 0; r < 4; ++r) {
                    const float p = __expf(sv[ns][r] - m_i[r]);
                    pv[ns][r] = p;
                    rs[r] += p;
                }
#pragma unroll
            for (int off = 8; off >= 1; off >>= 1)
#pragma unroll
                for (int r = 0; r < 4; ++r)
                    rs[r] += __shfl_xor(rs[r], off, 64);
#pragma unroll
            for (int r = 0; r < 4; ++r)
                l_i[r] = l_i[r] * al[r] + rs[r];
#pragma unroll
            for (int d = 0; d < 4; ++d)
#pragma unroll
                for (int r = 0; r < 4; ++r)
                    o[d][r] = o[d][r] * al[r];

            // P: C-layout -> A-layout via per-wave LDS (no barrier needed: same-wave RAW)
#pragma unroll
            for (int ns = 0; ns < 4; ++ns)
#pragma unroll
                for (int r = 0; r < 4; ++r)
                    Ps[wave][(quad * 4 + r) * LDSW + ns * 16 + l16] =
                        (unsigned short)(__float_as_uint(pv[ns][r]) >> 16);   // trunc, p>=0

            const bf16x8 pf0 = *(const bf16x8*)&Ps[wave][l16 * LDSW + quad * 8];
            const bf16x8 pf1 = *(const bf16x8*)&Ps[wave][l16 * LDSW + 32 + quad * 8];
#pragma unroll
            for (int d = 0; d < 4; ++d) {
                const bf16x8 v0 = *(const bf16x8*)&Vs[buf][(d * 16 + l16) * LDSW + quad * 8];
                const bf16x8 v1 = *(const bf16x8*)&Vs[buf][(d * 16 + l16) * LDSW + 32 + quad * 8];
                o[d] = __builtin_amdgcn_mfma_f32_16x16x32_bf16(pf0, v0, o[d], 0, 0, 0);
                o[d] = __builtin_amdgcn_mfma_f32_16x16x32_bf16(pf1, v1, o[d], 0, 0, 0);
            }
        }

        if (pre) {   // write prefetched tile into the other buffer
            *(ushortx8*)&Ks[buf ^ 1][krow * LDSW + kc] = kreg;
#pragma unroll
            for (int i = 0; i < 8; ++i) Vs[buf ^ 1][(vdc * 8 + i) * LDSW + vrow] = vreg[i];
        }
        __syncthreads();
    }

    if (qb < 8) {
        // single chunk: normalized write
#pragma unroll
        for (int r = 0; r < 4; ++r) {
            const float inv = 1.0f / l_i[r];
            const int qr = qminw + quad * 4 + r;
#pragma unroll
            for (int d = 0; d < 4; ++d)
                AO[(size_t)qr * DMODEL + h * 64 + d * 16 + l16] = f2bf(o[d][r] * inv);
        }
    } else {
        static const int coff[4] = {0, 32, 56, 72};
        const int slot = h * WPH + coff[c] + (qb - 8 * c);
        unsigned short* op = Opart + (size_t)slot * (128 * 64);
#pragma unroll
        for (int d = 0; d < 4; ++d)
#pragma unroll
            for (int r = 0; r < 4; ++r)
                op[(wave * 16 + quad * 4 + r) * 64 + d * 16 + l16] = f2bf(o[d][r]);
        if (l16 == 0) {
            float* mlp = ml + (size_t)slot * 256;
#pragma unroll
            for (int r = 0; r < 4; ++r) {
                const int row = wave * 16 + quad * 4 + r;
                mlp[row * 2]     = m_i[r];
                mlp[row * 2 + 1] = l_i[r];
            }
        }
    }
}

// ---------------- combine chunk partials ----------------
// grid (24, 12): qb = 8+x, h = y. thread: row = tid>>1 (0..127), 32 d at (tid&1)*32.
__global__ __launch_bounds__(256) void combine(
    const unsigned short* __restrict__ Opart,
    const float* __restrict__ ml,
    unsigned short* __restrict__ AO)
{
    const int qb  = 8 + blockIdx.x;
    const int h   = blockIdx.y;
    const int row = threadIdx.x >> 1;
    const int ds  = (threadIdx.x & 1) * 32;
    const int nc  = (qb >> 3) + 1;
    static const int coff[4] = {0, 32, 56, 72};

    int slots[4];
    for (int cI = 0; cI < 4; ++cI) slots[cI] = h * WPH + coff[cI] + (qb - 8 * cI);

    float mc[4], lc[4];
    float M = -3e38f;
    for (int cI = 0; cI < nc; ++cI) {
        mc[cI] = ml[(size_t)slots[cI] * 256 + row * 2];
        lc[cI] = ml[(size_t)slots[cI] * 256 + row * 2 + 1];
        M = fmaxf(M, mc[cI]);
    }
    float L = 0.f;
    float acc[32];
#pragma unroll
    for (int i = 0; i < 32; ++i) acc[i] = 0.f;

    for (int cI = 0; cI < nc; ++cI) {
        const float sc = __expf(mc[cI] - M);
        L += sc * lc[cI];
        const unsigned short* op = Opart + (size_t)slots[cI] * (128 * 64) + row * 64 + ds;
#pragma unroll
        for (int g = 0; g < 4; ++g) {
            const ushortx8 a = *(const ushortx8*)(op + g * 8);
#pragma unroll
            for (int i = 0; i < 8; ++i) acc[g * 8 + i] += sc * bf2f(a[i]);
        }
    }
    const float inv = 1.0f / L;
    unsigned short* dst = AO + (size_t)(qb * 128 + row) * DMODEL + h * 64 + ds;
#pragma unroll
    for (int g = 0; g < 4; ++g) {
        ushortx8 ov;
#pragma unroll
        for (int i = 0; i < 8; ++i) ov[i] = f2bf(acc[g * 8 + i] * inv);
        *(ushortx8*)(dst + g * 8) = ov;
    }
}

extern "C" void kernel_launch(void* const* d_in, const int* in_sizes, int n_in,
                              void* d_out, int out_size, void* d_ws, size_t ws_size,
                              hipStream_t stream) {
    const float* x  = (const float*)d_in[0];
    const float* Wq = (const float*)d_in[1];
    const float* Wk = (const float*)d_in[2];
    const float* Wv = (const float*)d_in[3];
    const float* Wo = (const float*)d_in[4];

    const int xElems = S_LEN * DMODEL;
    const int wElems = DMODEL * DMODEL;
    const size_t headElems = (size_t)NHEADS * S_LEN * 64;
    const int nslots = NHEADS * WPH;   // 960

    unsigned short* xb  = (unsigned short*)d_ws;
    unsigned short* Wqb = xb  + xElems;
    unsigned short* Wkb = Wqb + wElems;
    unsigned short* Wvb = Wkb + wElems;
    unsigned short* Wob = Wvb + wElems;
    unsigned short* Qh  = Wob + wElems;
    unsigned short* Kh  = Qh + headElems;
    unsigned short* Vh  = Kh + headElems;
    unsigned short* AO  = Vh + headElems;
    unsigned short* Opart = AO + xElems;                    // [960][128*64] bf16
    float* ml = (float*)(Opart + (size_t)nslots * 128 * 64); // [960][256] fp32

    cvt_all<<<dim3(2688), dim3(256), 0, stream>>>(x, Wq, Wk, Wv, Wo,
                                                  xb, Wqb, Wkb, Wvb, Wob);

    gemm_nt<1><<<dim3(DMODEL / 128, S_LEN / 128, 3), dim3(256), 0, stream>>>(
        xb, Wqb, Wkb, Wvb, Qh, Kh, Vh, nullptr, S_LEN, DMODEL, DMODEL);

    flash_part<<<dim3(WPH, NHEADS), dim3(512), 0, stream>>>(Qh, Kh, Vh, AO, Opart, ml);

    combine<<<dim3(24, NHEADS), dim3(256), 0, stream>>>(Opart, ml, AO);

    gemm_nt<0><<<dim3(DMODEL / 128, S_LEN / 128, 1), dim3(256), 0, stream>>>(
        AO, Wob, nullptr, nullptr, nullptr, nullptr, nullptr,
        (float*)d_out, S_LEN, DMODEL, DMODEL);
}

// Round 7
// 223.457 us; speedup vs baseline: 1.7936x; 1.0769x over previous
//
#include <hip/hip_runtime.h>
#include <hip/hip_bf16.h>
#include <stdint.h>

// MultiHeadSelfAttention, B=1, S=4096, D_MODEL=768, H=12, Dk=64, causal.
// FP32 I/O, bf16 MFMA inside. Launches:
//   0) cvt_all    fp32->bf16
//   1) gemm_nt<1> QKV projections -> Q,K [H][S][64] bf16, V TRANSPOSED [H][64][S]
//   2) flash_part causal flash attention, S^T formulation:
//        S^T = K Q^T  (A=K from LDS, B=Q in regs) -> C-layout col=q
//        P -> PV A-operand via in-reg pack + ds_bpermute (no LDS round trip)
//        O = P V (B=V^T from LDS b128)
//      q-tile 128 (4 waves x 32 q), KV chunks of 1024, double-buffered LDS.
//   3) combine    merge chunk partials -> AO
//   4) gemm_nt<0> AO @ Wo^T -> d_out fp32
// R6 FIX: __shfl evaluates its operand in the SOURCE lane -> tile selection
// must happen on the DEST side. Shuffle both tiles, cndmask by dest quad.

#define S_LEN  4096
#define DMODEL 768
#define NHEADS 12
#define LDSW   72          // padded LDS row stride (elems)
#define WPH    80          // work items per head: 32 + 24 + 16 + 8

typedef __attribute__((ext_vector_type(8))) __bf16 bf16x8;
typedef __attribute__((ext_vector_type(8))) unsigned short ushortx8;
typedef __attribute__((ext_vector_type(4))) unsigned short ushortx4;
typedef __attribute__((ext_vector_type(4))) unsigned int uintx4;
typedef __attribute__((ext_vector_type(4))) float floatx4;

__device__ __forceinline__ unsigned short f2bf(float f) {
    unsigned int u = __float_as_uint(f);
    u += 0x7fffu + ((u >> 16) & 1u);   // RNE
    return (unsigned short)(u >> 16);
}
__device__ __forceinline__ float bf2f(unsigned short v) {
    return __uint_as_float(((unsigned int)v) << 16);
}

// ---------------- fused fp32->bf16 conversion ----------------
__global__ __launch_bounds__(256) void cvt_all(
    const float* __restrict__ x,  const float* __restrict__ Wq,
    const float* __restrict__ Wk, const float* __restrict__ Wv,
    const float* __restrict__ Wo,
    unsigned short* __restrict__ xb,  unsigned short* __restrict__ Wqb,
    unsigned short* __restrict__ Wkb, unsigned short* __restrict__ Wvb,
    unsigned short* __restrict__ Wob)
{
    int b = blockIdx.x;
    const float* src; unsigned short* dst;
    if (b < 1536)      { src = x;  dst = xb;  }
    else if (b < 1824) { src = Wq; dst = Wqb; b -= 1536; }
    else if (b < 2112) { src = Wk; dst = Wkb; b -= 1824; }
    else if (b < 2400) { src = Wv; dst = Wvb; b -= 2112; }
    else               { src = Wo; dst = Wob; b -= 2400; }
    const int i = (b * 256 + threadIdx.x) * 8;
    const float4 a0 = *(const float4*)(src + i);
    const float4 a1 = *(const float4*)(src + i + 4);
    ushortx8 o;
    o[0] = f2bf(a0.x); o[1] = f2bf(a0.y); o[2] = f2bf(a0.z); o[3] = f2bf(a0.w);
    o[4] = f2bf(a1.x); o[5] = f2bf(a1.y); o[6] = f2bf(a1.z); o[7] = f2bf(a1.w);
    *(ushortx8*)(dst + i) = o;
}

// ---------------- GEMM C = A * B^T ----------------
// MODE 0: fp32 out [M][N]. MODE 1: z=0 Q, z=1 K head-major [H][M][64];
// z=2 V stored TRANSPOSED: C2[(h*64+d)*M + m] with packed b64 stores.
template <int MODE>
__global__ __launch_bounds__(256) void gemm_nt(
    const unsigned short* __restrict__ A,
    const unsigned short* __restrict__ B0,
    const unsigned short* __restrict__ B1,
    const unsigned short* __restrict__ B2,
    unsigned short* __restrict__ C0,
    unsigned short* __restrict__ C1,
    unsigned short* __restrict__ C2,
    float* __restrict__ Cf,
    int M, int N, int K)
{
    __shared__ __align__(16) unsigned short As[128 * 32];
    __shared__ __align__(16) unsigned short Bs[128 * 32];

    const int tid  = threadIdx.x;
    const int wave = tid >> 6;
    const int lane = tid & 63;
    const int quad = lane >> 4;
    const int l16  = lane & 15;
    const int wr   = wave >> 1;
    const int wc   = wave & 1;
    const int bm   = blockIdx.y * 128;
    const int bn   = blockIdx.x * 128;

    const unsigned short* B = B0;
    unsigned short* C = C0;
    if (MODE == 1) {
        if (blockIdx.z == 1)      { B = B1; C = C1; }
        else if (blockIdx.z == 2) { B = B2; C = C2; }
    }

    floatx4 acc[4][4];
    const floatx4 zf = {0.f, 0.f, 0.f, 0.f};
#pragma unroll
    for (int i = 0; i < 4; ++i)
#pragma unroll
        for (int j = 0; j < 4; ++j) acc[i][j] = zf;

    const int srow = tid >> 1;
    const int scg  = (tid & 1) * 16;

    for (int kb = 0; kb < K; kb += 32) {
        __syncthreads();
        const unsigned short* ap = A + (size_t)(bm + srow) * K + kb + scg;
        const unsigned short* bp = B + (size_t)(bn + srow) * K + kb + scg;
        const ushortx8 a0 = *(const ushortx8*)ap;
        const ushortx8 a1 = *(const ushortx8*)(ap + 8);
        const ushortx8 b0 = *(const ushortx8*)bp;
        const ushortx8 b1 = *(const ushortx8*)(bp + 8);
        *(ushortx8*)&As[srow * 32 + scg]     = a0;
        *(ushortx8*)&As[srow * 32 + scg + 8] = a1;
        *(ushortx8*)&Bs[srow * 32 + scg]     = b0;
        *(ushortx8*)&Bs[srow * 32 + scg + 8] = b1;
        __syncthreads();

        bf16x8 af[4], bfr[4];
#pragma unroll
        for (int i = 0; i < 4; ++i) {
            af[i]  = *(const bf16x8*)&As[(wr * 64 + i * 16 + l16) * 32 + quad * 8];
            bfr[i] = *(const bf16x8*)&Bs[(wc * 64 + i * 16 + l16) * 32 + quad * 8];
        }
#pragma unroll
        for (int mi = 0; mi < 4; ++mi)
#pragma unroll
            for (int ni = 0; ni < 4; ++ni)
                acc[mi][ni] = __builtin_amdgcn_mfma_f32_16x16x32_bf16(af[mi], bfr[ni], acc[mi][ni], 0, 0, 0);
    }

#pragma unroll
    for (int mi = 0; mi < 4; ++mi) {
#pragma unroll
        for (int ni = 0; ni < 4; ++ni) {
            const floatx4 v = acc[mi][ni];
            const int n = bn + wc * 64 + ni * 16 + l16;
            const int m0 = bm + wr * 64 + mi * 16 + quad * 4;
            if (MODE == 1 && blockIdx.z == 2) {
                // V transposed: Vt[(h*64+d)][m], 4 consecutive m -> b64 store
                const int hh = n >> 6, d = n & 63;
                ushortx4 pv;
#pragma unroll
                for (int r = 0; r < 4; ++r) pv[r] = f2bf(v[r]);
                *(ushortx4*)&C[(size_t)(hh * 64 + d) * M + m0] = pv;
            } else {
#pragma unroll
                for (int r = 0; r < 4; ++r) {
                    const int m = m0 + r;
                    if (MODE == 0) {
                        Cf[(size_t)m * N + n] = v[r];
                    } else {
                        const int hh = n >> 6, d = n & 63;
                        C[((size_t)hh * M + m) * 64 + d] = f2bf(v[r]);
                    }
                }
            }
        }
    }
}

// ---------------- flash attention, S^T formulation ----------------
// grid (WPH, NHEADS), 256 thr = 4 waves, each wave 32 q (2 qblks of 16).
__global__ __launch_bounds__(256) void flash_part(
    const unsigned short* __restrict__ Qh,
    const unsigned short* __restrict__ Kh,
    const unsigned short* __restrict__ VhT,   // [H][64][S]
    unsigned short* __restrict__ AO,
    unsigned short* __restrict__ Opart,
    float* __restrict__ ml)
{
    __shared__ __align__(16) unsigned short Ks[2][64 * LDSW];   // [kv][d]
    __shared__ __align__(16) unsigned short Vs[2][64 * LDSW];   // [d][kv]

    const int tid  = threadIdx.x;
    const int wave = tid >> 6;
    const int lane = tid & 63;
    const int quad = lane >> 4;
    const int l16  = lane & 15;
    const int h    = blockIdx.y;
    const int w    = blockIdx.x;

    int c, qb;
    if (w < 32)      { c = 0; qb = w; }
    else if (w < 56) { c = 1; qb = 8  + (w - 32); }
    else if (w < 72) { c = 2; qb = 16 + (w - 56); }
    else             { c = 3; qb = 24 + (w - 72); }

    const int q0       = qb * 128;
    const int kv_start = c * 1024;
    const int kv_end   = min(kv_start + 1024, q0 + 128);
    const int ntiles   = (kv_end - kv_start) >> 6;
    const int qbase    = q0 + wave * 32;

    const unsigned short* Qb  = Qh  + (size_t)h * S_LEN * 64;
    const unsigned short* Kb  = Kh  + (size_t)h * S_LEN * 64;
    const unsigned short* Vtb = VhT + (size_t)h * 64 * S_LEN;

    // Q B-frags (n=q=l16, k=d=quad*8+j), held for whole block
    bf16x8 qf[2][2];
#pragma unroll
    for (int b = 0; b < 2; ++b)
#pragma unroll
        for (int kc = 0; kc < 2; ++kc)
            qf[b][kc] = *(const bf16x8*)&Qb[(size_t)(qbase + b * 16 + l16) * 64 + kc * 32 + quad * 8];

    float m_i[2] = {-1e30f, -1e30f}, l_i[2] = {0.f, 0.f};
    floatx4 o[2][4];
    const floatx4 zf = {0.f, 0.f, 0.f, 0.f};
#pragma unroll
    for (int b = 0; b < 2; ++b)
#pragma unroll
        for (int d = 0; d < 4; ++d) o[b][d] = zf;

    const int srow = tid >> 2;           // 0..63
    const int scol = (tid & 3) * 16;     // 0,16,32,48
    const int asrc = quad << 2;          // shfl src base for per-row factors
    const int psrc = l16 + ((quad & 1) << 5);   // bpermute src lanes (and +16)

    // prologue: stage tile 0 into buf 0
    {
        const unsigned short* kp = Kb + (size_t)(kv_start + srow) * 64 + scol;
        const unsigned short* vp = Vtb + (size_t)srow * S_LEN + kv_start + scol;
        const ushortx8 k0 = *(const ushortx8*)kp;
        const ushortx8 k1 = *(const ushortx8*)(kp + 8);
        const ushortx8 v0 = *(const ushortx8*)vp;
        const ushortx8 v1 = *(const ushortx8*)(vp + 8);
        *(ushortx8*)&Ks[0][srow * LDSW + scol]     = k0;
        *(ushortx8*)&Ks[0][srow * LDSW + scol + 8] = k1;
        *(ushortx8*)&Vs[0][srow * LDSW + scol]     = v0;
        *(ushortx8*)&Vs[0][srow * LDSW + scol + 8] = v1;
    }
    __syncthreads();

    for (int t = 0; t < ntiles; ++t) {
        const int buf = t & 1;
        const int kv0 = kv_start + t * 64;
        const bool pre = (t + 1 < ntiles);

        ushortx8 kr0, kr1, vr0, vr1;
        if (pre) {
            const unsigned short* kp = Kb + (size_t)(kv0 + 64 + srow) * 64 + scol;
            const unsigned short* vp = Vtb + (size_t)srow * S_LEN + kv0 + 64 + scol;
            kr0 = *(const ushortx8*)kp;  kr1 = *(const ushortx8*)(kp + 8);
            vr0 = *(const ushortx8*)vp;  vr1 = *(const ushortx8*)(vp + 8);
        }

        if (kv0 <= qbase + 31) {   // wave has unmasked work in this tile
            // S^T = K Q^T : D[m=kv][n=q]
            floatx4 sv[2][4];
#pragma unroll
            for (int b = 0; b < 2; ++b)
#pragma unroll
                for (int ns = 0; ns < 4; ++ns) sv[b][ns] = zf;
#pragma unroll
            for (int ns = 0; ns < 4; ++ns) {
                const bf16x8 kf0 = *(const bf16x8*)&Ks[buf][(ns * 16 + l16) * LDSW + quad * 8];
                const bf16x8 kf1 = *(const bf16x8*)&Ks[buf][(ns * 16 + l16) * LDSW + 32 + quad * 8];
                sv[0][ns] = __builtin_amdgcn_mfma_f32_16x16x32_bf16(kf0, qf[0][0], sv[0][ns], 0, 0, 0);
                sv[0][ns] = __builtin_amdgcn_mfma_f32_16x16x32_bf16(kf1, qf[0][1], sv[0][ns], 0, 0, 0);
                sv[1][ns] = __builtin_amdgcn_mfma_f32_16x16x32_bf16(kf0, qf[1][0], sv[1][ns], 0, 0, 0);
                sv[1][ns] = __builtin_amdgcn_mfma_f32_16x16x32_bf16(kf1, qf[1][1], sv[1][ns], 0, 0, 0);
            }

            const bool domask = (kv0 + 63 > qbase);
            unsigned int pk[2][4][2];
            float al[2];
#pragma unroll
            for (int b = 0; b < 2; ++b) {
                const int qcol = qbase + b * 16 + l16;   // this lane's q
                if (domask) {
#pragma unroll
                    for (int ns = 0; ns < 4; ++ns)
#pragma unroll
                        for (int r = 0; r < 4; ++r) {
                            float v = sv[b][ns][r] * 0.125f;
                            if (kv0 + ns * 16 + quad * 4 + r > qcol) v = -1e9f;
                            sv[b][ns][r] = v;
                        }
                } else {
#pragma unroll
                    for (int ns = 0; ns < 4; ++ns)
#pragma unroll
                        for (int r = 0; r < 4; ++r)
                            sv[b][ns][r] = sv[b][ns][r] * 0.125f;
                }
                float mx = sv[b][0][0];
#pragma unroll
                for (int ns = 0; ns < 4; ++ns)
#pragma unroll
                    for (int r = 0; r < 4; ++r) mx = fmaxf(mx, sv[b][ns][r]);
                mx = fmaxf(mx, __shfl_xor(mx, 16, 64));
                mx = fmaxf(mx, __shfl_xor(mx, 32, 64));
                const float mn = fmaxf(m_i[b], mx);
                al[b] = __expf(m_i[b] - mn);
                m_i[b] = mn;
                float rs = 0.f;
#pragma unroll
                for (int ns = 0; ns < 4; ++ns)
#pragma unroll
                    for (int r = 0; r < 4; ++r) {
                        const float p = __expf(sv[b][ns][r] - mn);
                        sv[b][ns][r] = p;
                        rs += p;
                    }
                rs += __shfl_xor(rs, 16, 64);
                rs += __shfl_xor(rs, 32, 64);
                l_i[b] = l_i[b] * al[b] + rs;
                // pack P rows pairwise to bf16 (trunc) for the bpermute pass
#pragma unroll
                for (int ns = 0; ns < 4; ++ns)
#pragma unroll
                    for (int rr = 0; rr < 2; ++rr)
                        pk[b][ns][rr] = (__float_as_uint(sv[b][ns][2 * rr + 1]) & 0xffff0000u)
                                      | (__float_as_uint(sv[b][ns][2 * rr]) >> 16);
                // rescale O rows (factor per row via shfl; operand uniform across lanes)
#pragma unroll
                for (int r = 0; r < 4; ++r) {
                    const float a = __shfl(al[b], asrc + r, 64);
#pragma unroll
                    for (int d = 0; d < 4; ++d) o[b][d][r] *= a;
                }
            }

            // O += P V : A = P (bpermute BOTH tiles, select by dest quad), B = V^T
#pragma unroll
            for (int kc2 = 0; kc2 < 2; ++kc2) {
                bf16x8 af[2];
#pragma unroll
                for (int b = 0; b < 2; ++b) {
                    const unsigned int lo0 = pk[b][kc2 * 2][0],     lo1 = pk[b][kc2 * 2][1];
                    const unsigned int hi0 = pk[b][kc2 * 2 + 1][0], hi1 = pk[b][kc2 * 2 + 1][1];
                    uintx4 wlo, whi, aw;
                    wlo[0] = (unsigned int)__shfl((int)lo0, psrc, 64);
                    wlo[1] = (unsigned int)__shfl((int)lo1, psrc, 64);
                    wlo[2] = (unsigned int)__shfl((int)lo0, psrc + 16, 64);
                    wlo[3] = (unsigned int)__shfl((int)lo1, psrc + 16, 64);
                    whi[0] = (unsigned int)__shfl((int)hi0, psrc, 64);
                    whi[1] = (unsigned int)__shfl((int)hi1, psrc, 64);
                    whi[2] = (unsigned int)__shfl((int)hi0, psrc + 16, 64);
                    whi[3] = (unsigned int)__shfl((int)hi1, psrc + 16, 64);
#pragma unroll
                    for (int i = 0; i < 4; ++i) aw[i] = (quad >= 2) ? whi[i] : wlo[i];
                    af[b] = __builtin_bit_cast(bf16x8, aw);
                }
#pragma unroll
                for (int d = 0; d < 4; ++d) {
                    const bf16x8 vf = *(const bf16x8*)&Vs[buf][(d * 16 + l16) * LDSW + kc2 * 32 + quad * 8];
                    o[0][d] = __builtin_amdgcn_mfma_f32_16x16x32_bf16(af[0], vf, o[0][d], 0, 0, 0);
                    o[1][d] = __builtin_amdgcn_mfma_f32_16x16x32_bf16(af[1], vf, o[1][d], 0, 0, 0);
                }
            }
        }

        if (pre) {
            *(ushortx8*)&Ks[buf ^ 1][srow * LDSW + scol]     = kr0;
            *(ushortx8*)&Ks[buf ^ 1][srow * LDSW + scol + 8] = kr1;
            *(ushortx8*)&Vs[buf ^ 1][srow * LDSW + scol]     = vr0;
            *(ushortx8*)&Vs[buf ^ 1][srow * LDSW + scol + 8] = vr1;
        }
        __syncthreads();
    }

    // epilogue. O layout: col d = dblk*16+l16, row q = quad*4+r (per qblk)
    if (qb < 8) {
#pragma unroll
        for (int b = 0; b < 2; ++b) {
            const float invl = 1.0f / l_i[b];
#pragma unroll
            for (int r = 0; r < 4; ++r) {
                const float a = __shfl(invl, asrc + r, 64);
                const int qr = qbase + b * 16 + quad * 4 + r;
#pragma unroll
                for (int d = 0; d < 4; ++d)
                    AO[(size_t)qr * DMODEL + h * 64 + d * 16 + l16] = f2bf(o[b][d][r] * a);
            }
        }
    } else {
        static const int coff[4] = {0, 32, 56, 72};
        const int slot = h * WPH + coff[c] + (qb - 8 * c);
        unsigned short* op = Opart + (size_t)slot * (128 * 64);
#pragma unroll
        for (int b = 0; b < 2; ++b)
#pragma unroll
            for (int r = 0; r < 4; ++r) {
                const int lr = wave * 32 + b * 16 + quad * 4 + r;
#pragma unroll
                for (int d = 0; d < 4; ++d)
                    op[lr * 64 + d * 16 + l16] = f2bf(o[b][d][r]);
            }
        if (quad == 0) {
            float* mlp = ml + (size_t)slot * 256;
#pragma unroll
            for (int b = 0; b < 2; ++b) {
                const int lr = wave * 32 + b * 16 + l16;
                mlp[lr * 2]     = m_i[b];
                mlp[lr * 2 + 1] = l_i[b];
            }
        }
    }
}

// ---------------- combine chunk partials ----------------
__global__ __launch_bounds__(256) void combine(
    const unsigned short* __restrict__ Opart,
    const float* __restrict__ ml,
    unsigned short* __restrict__ AO)
{
    const int qb  = 8 + blockIdx.x;
    const int h   = blockIdx.y;
    const int row = threadIdx.x >> 1;
    const int ds  = (threadIdx.x & 1) * 32;
    const int nc  = (qb >> 3) + 1;
    static const int coff[4] = {0, 32, 56, 72};

    int slots[4];
    for (int cI = 0; cI < 4; ++cI) slots[cI] = h * WPH + coff[cI] + (qb - 8 * cI);

    float mc[4], lc[4];
    float M = -3e38f;
    for (int cI = 0; cI < nc; ++cI) {
        mc[cI] = ml[(size_t)slots[cI] * 256 + row * 2];
        lc[cI] = ml[(size_t)slots[cI] * 256 + row * 2 + 1];
        M = fmaxf(M, mc[cI]);
    }
    float L = 0.f;
    float acc[32];
#pragma unroll
    for (int i = 0; i < 32; ++i) acc[i] = 0.f;

    for (int cI = 0; cI < nc; ++cI) {
        const float sc = __expf(mc[cI] - M);
        L += sc * lc[cI];
        const unsigned short* op = Opart + (size_t)slots[cI] * (128 * 64) + row * 64 + ds;
#pragma unroll
        for (int g = 0; g < 4; ++g) {
            const ushortx8 a = *(const ushortx8*)(op + g * 8);
#pragma unroll
            for (int i = 0; i < 8; ++i) acc[g * 8 + i] += sc * bf2f(a[i]);
        }
    }
    const float inv = 1.0f / L;
    unsigned short* dst = AO + (size_t)(qb * 128 + row) * DMODEL + h * 64 + ds;
#pragma unroll
    for (int g = 0; g < 4; ++g) {
        ushortx8 ov;
#pragma unroll
        for (int i = 0; i < 8; ++i) ov[i] = f2bf(acc[g * 8 + i] * inv);
        *(ushortx8*)(dst + g * 8) = ov;
    }
}

extern "C" void kernel_launch(void* const* d_in, const int* in_sizes, int n_in,
                              void* d_out, int out_size, void* d_ws, size_t ws_size,
                              hipStream_t stream) {
    const float* x  = (const float*)d_in[0];
    const float* Wq = (const float*)d_in[1];
    const float* Wk = (const float*)d_in[2];
    const float* Wv = (const float*)d_in[3];
    const float* Wo = (const float*)d_in[4];

    const int xElems = S_LEN * DMODEL;
    const int wElems = DMODEL * DMODEL;
    const size_t headElems = (size_t)NHEADS * S_LEN * 64;
    const int nslots = NHEADS * WPH;   // 960

    unsigned short* xb  = (unsigned short*)d_ws;
    unsigned short* Wqb = xb  + xElems;
    unsigned short* Wkb = Wqb + wElems;
    unsigned short* Wvb = Wkb + wElems;
    unsigned short* Wob = Wvb + wElems;
    unsigned short* Qh  = Wob + wElems;
    unsigned short* Kh  = Qh + headElems;
    unsigned short* Vt  = Kh + headElems;                    // [H][64][S]
    unsigned short* AO  = Vt + headElems;
    unsigned short* Opart = AO + xElems;                     // [960][128*64]
    float* ml = (float*)(Opart + (size_t)nslots * 128 * 64); // [960][256]

    cvt_all<<<dim3(2688), dim3(256), 0, stream>>>(x, Wq, Wk, Wv, Wo,
                                                  xb, Wqb, Wkb, Wvb, Wob);

    gemm_nt<1><<<dim3(DMODEL / 128, S_LEN / 128, 3), dim3(256), 0, stream>>>(
        xb, Wqb, Wkb, Wvb, Qh, Kh, Vt, nullptr, S_LEN, DMODEL, DMODEL);

    flash_part<<<dim3(WPH, NHEADS), dim3(256), 0, stream>>>(Qh, Kh, Vt, AO, Opart, ml);

    combine<<<dim3(24, NHEADS), dim3(256), 0, stream>>>(Opart, ml, AO);

    gemm_nt<0><<<dim3(DMODEL / 128, S_LEN / 128, 1), dim3(256), 0, stream>>>(
        AO, Wob, nullptr, nullptr, nullptr, nullptr, nullptr,
        (float*)d_out, S_LEN, DMODEL, DMODEL);
}